// Round 2
// baseline (161.090 us; speedup 1.0000x reference)
//
#include <hip/hip_runtime.h>

// Output is a discrete color pick via fp32 sign tests -> predicates must match
// numpy fp32 rounding bit-exactly. File-wide contract(off) keeps the EXACT
// paths exact; the screen path uses explicit __builtin_fmaf (deterministic).
#pragma clang fp contract(off)

#define NPTS 2097152

// ws float layout:
//   TRI  [25][12]: ax,ay,d0y,d0x, bx,by,d1y,d1x, cx,cy,d2y,d2x   (d* are numpy-rounded fp32 diffs)
//   CIRC [25][8] : ocx,ocy,r2, r2-epsC, r2+epsC, pad,pad,pad
//   ELL  [25][8] : ecx,ecy, 1/erx, 1/ery, erx, ery, pad,pad
//   COL  [75][4] : r,g,b,pad
#define TRI_OFF  0
#define CIRC_OFF 300
#define ELL_OFF  500
#define COL_OFF  700

// Screen epsilons. Screen-vs-numpy error bounds (hand-derived, >=10x margin):
//   tri:   <= ~3 ulp(0.16) ~ 3.6e-8   -> EPS_T = 5e-7
//   circ:  <= ~2 ulp(0.004) ~ 1e-9    -> EPS_C = 1e-8
//   ell:   recip-vs-div rel ~2.4e-7 on t~1 -> EPS_E = 1e-5 (proven round 1)
#define EPS_T 5e-7f
#define EPS_C 1e-8f
#define EPS_E 1e-5f

__global__ void vg_precompute(const float* __restrict__ p, float* __restrict__ ws) {
    int t = threadIdx.x;
    if (t < 25) {
        const float* cell = p + t * 28;
        float ax = cell[1], ay = cell[2], bx = cell[3], by = cell[4], cx = cell[5], cy = cell[6];
        float* o = ws + TRI_OFF + t * 12;
        o[0] = ax; o[1] = ay; o[2]  = by - ay; o[3]  = bx - ax;
        o[4] = bx; o[5] = by; o[6]  = cy - by; o[7]  = cx - bx;
        o[8] = cx; o[9] = cy; o[10] = ay - cy; o[11] = ax - cx;
        float* col = ws + COL_OFF + (3 * t + 0) * 4;
        col[0] = cell[8]; col[1] = cell[9]; col[2] = cell[10]; col[3] = 0.f;
    } else if (t < 50) {
        int c = t - 25;
        const float* cell = p + c * 28;
        float ocx = cell[12], ocy = cell[13], orr = cell[14];
        float r2 = orr * orr;  // numpy rounding
        float* o = ws + CIRC_OFF + c * 8;
        o[0] = ocx; o[1] = ocy; o[2] = r2; o[3] = r2 - EPS_C; o[4] = r2 + EPS_C;
        o[5] = 0.f; o[6] = 0.f; o[7] = 0.f;
        float* col = ws + COL_OFF + (3 * c + 1) * 4;
        col[0] = cell[16]; col[1] = cell[17]; col[2] = cell[18]; col[3] = 0.f;
    } else if (t < 75) {
        int c = t - 50;
        const float* cell = p + c * 28;
        float ecx = cell[20], ecy = cell[21], erx = cell[22], ery = cell[23];
        float* o = ws + ELL_OFF + c * 8;
        o[0] = ecx; o[1] = ecy; o[2] = 1.0f / erx; o[3] = 1.0f / ery;
        o[4] = erx; o[5] = ery; o[6] = 0.f; o[7] = 0.f;
        float* col = ws + COL_OFF + (3 * c + 2) * 4;
        col[0] = cell[25]; col[1] = cell[26]; col[2] = cell[27]; col[3] = 0.f;
    }
}

// Bit-exact numpy-order evaluation (real IEEE divides). Rare path: only for
// points within eps of some shape boundary (~0.03% of points).
__device__ __noinline__ int exact_point(float px, float py, const float* __restrict__ ws) {
    int idx = -1;
#pragma clang loop unroll(disable)
    for (int c = 0; c < 25; ++c) {
        const float* tc = ws + TRI_OFF + c * 12;
        float e0 = (px - tc[0]) * tc[2]  - (py - tc[1]) * tc[3];
        float e1 = (px - tc[4]) * tc[6]  - (py - tc[5]) * tc[7];
        float e2 = (px - tc[8]) * tc[10] - (py - tc[9]) * tc[11];
        bool tin = (e0 >= 0.f && e1 >= 0.f && e2 >= 0.f) ||
                   (e0 <= 0.f && e1 <= 0.f && e2 <= 0.f);
        if (tin) idx = 3 * c;
        const float* cc = ws + CIRC_OFF + c * 8;
        float dx = px - cc[0], dy = py - cc[1];
        if (dx * dx + dy * dy <= cc[2]) idx = 3 * c + 1;
        const float* ec = ws + ELL_OFF + c * 8;
        float u = (px - ec[0]) / ec[4];   // IEEE division, numpy order
        float v = (py - ec[1]) / ec[5];
        if (u * u + v * v <= 1.0f) idx = 3 * c + 2;
    }
    return idx;
}

__global__ __launch_bounds__(256) void vg_main(const float* __restrict__ x,
                                               const float* __restrict__ ws,
                                               float* __restrict__ out) {
    int t = blockIdx.x * 256 + threadIdx.x;   // handles points 2t, 2t+1

    float4 xv = ((const float4*)x)[t];
    float pxA = xv.x, pyA = xv.y, pxB = xv.z, pyB = xv.w;

    int idxA = -1, idxB = -1;
    bool uncA = false, uncB = false;

#pragma unroll
    for (int c = 0; c < 25; ++c) {
        // ---------- triangle (shape 3c): fma screen, 2-sided ----------
        const float* tc = ws + TRI_OFF + c * 12;
        float ax = tc[0], ay = tc[1], d0y = tc[2],  d0x = tc[3];
        float bx = tc[4], by = tc[5], d1y = tc[6],  d1x = tc[7];
        float cx = tc[8], cy = tc[9], d2y = tc[10], d2x = tc[11];
        {
            float e0 = __builtin_fmaf(pxA - ax, d0y, -((pyA - ay) * d0x));
            float e1 = __builtin_fmaf(pxA - bx, d1y, -((pyA - by) * d1x));
            float e2 = __builtin_fmaf(pxA - cx, d2y, -((pyA - cy) * d2x));
            float lo = __builtin_fminf(__builtin_fminf(e0, e1), e2);
            float hi = __builtin_fmaxf(__builtin_fmaxf(e0, e1), e2);
            bool sin_ = (lo >= EPS_T) || (hi <= -EPS_T);
            bool rin_ = (lo >= -EPS_T) || (hi <= EPS_T);
            uncA |= (sin_ != rin_);
            idxA = sin_ ? 3 * c : idxA;
        }
        {
            float e0 = __builtin_fmaf(pxB - ax, d0y, -((pyB - ay) * d0x));
            float e1 = __builtin_fmaf(pxB - bx, d1y, -((pyB - by) * d1x));
            float e2 = __builtin_fmaf(pxB - cx, d2y, -((pyB - cy) * d2x));
            float lo = __builtin_fminf(__builtin_fminf(e0, e1), e2);
            float hi = __builtin_fmaxf(__builtin_fmaxf(e0, e1), e2);
            bool sin_ = (lo >= EPS_T) || (hi <= -EPS_T);
            bool rin_ = (lo >= -EPS_T) || (hi <= EPS_T);
            uncB |= (sin_ != rin_);
            idxB = sin_ ? 3 * c : idxB;
        }

        // ---------- circle (shape 3c+1) ----------
        const float* cc = ws + CIRC_OFF + c * 8;
        float ocx = cc[0], ocy = cc[1], r2lo = cc[3], r2hi = cc[4];
        {
            float dx = pxA - ocx, dy = pyA - ocy;
            float tt = __builtin_fmaf(dx, dx, dy * dy);
            bool sin_ = tt <= r2lo;
            bool rin_ = tt <= r2hi;
            uncA |= (sin_ != rin_);
            idxA = sin_ ? 3 * c + 1 : idxA;
        }
        {
            float dx = pxB - ocx, dy = pyB - ocy;
            float tt = __builtin_fmaf(dx, dx, dy * dy);
            bool sin_ = tt <= r2lo;
            bool rin_ = tt <= r2hi;
            uncB |= (sin_ != rin_);
            idxB = sin_ ? 3 * c + 1 : idxB;
        }

        // ---------- ellipse (shape 3c+2): reciprocal screen ----------
        const float* ec = ws + ELL_OFF + c * 8;
        float ecx = ec[0], ecy = ec[1], irx = ec[2], iry = ec[3];
        {
            float ex = pxA - ecx, ey = pyA - ecy;
            float ua = ex * irx, va = ey * iry;
            float tt = __builtin_fmaf(ua, ua, va * va);
            bool sin_ = tt <= (1.0f - EPS_E);
            bool rin_ = tt <= (1.0f + EPS_E);
            uncA |= (sin_ != rin_);
            idxA = sin_ ? 3 * c + 2 : idxA;
        }
        {
            float ex = pxB - ecx, ey = pyB - ecy;
            float ua = ex * irx, va = ey * iry;
            float tt = __builtin_fmaf(ua, ua, va * va);
            bool sin_ = tt <= (1.0f - EPS_E);
            bool rin_ = tt <= (1.0f + EPS_E);
            uncB |= (sin_ != rin_);
            idxB = sin_ ? 3 * c + 2 : idxB;
        }
    }

    // Rare exact fallback: one branch per point, full bit-exact re-evaluation.
    if (uncA) idxA = exact_point(pxA, pyA, ws);
    if (uncB) idxB = exact_point(pxB, pyB, ws);

    // Color gather + store (out[6t .. 6t+5], three 8B stores, coalesced).
    const float4* coltab = (const float4*)(ws + COL_OFF);
    int ciA = idxA < 0 ? 0 : idxA;
    int ciB = idxB < 0 ? 0 : idxB;
    float4 cA = coltab[ciA];
    float4 cB = coltab[ciB];
    if (idxA < 0) { cA.x = 0.f; cA.y = 0.f; cA.z = 0.f; }
    if (idxB < 0) { cB.x = 0.f; cB.y = 0.f; cB.z = 0.f; }

    float2* o2 = (float2*)out;
    o2[3 * t + 0] = make_float2(cA.x, cA.y);
    o2[3 * t + 1] = make_float2(cA.z, cB.x);
    o2[3 * t + 2] = make_float2(cB.y, cB.z);
}

extern "C" void kernel_launch(void* const* d_in, const int* in_sizes, int n_in,
                              void* d_out, int out_size, void* d_ws, size_t ws_size,
                              hipStream_t stream) {
    const float* x = (const float*)d_in[0];   // (NPTS, 2) fp32
    const float* p = (const float*)d_in[1];   // (700,)   fp32
    float* out = (float*)d_out;               // (NPTS, 3) fp32
    float* ws  = (float*)d_ws;                // >= 4 KB scratch

    vg_precompute<<<1, 128, 0, stream>>>(p, ws);
    vg_main<<<NPTS / 512, 256, 0, stream>>>(x, ws, out);
}

// Round 3
// 114.368 us; speedup vs baseline: 1.4085x; 1.4085x over previous
//
#include <hip/hip_runtime.h>

// Discrete color pick via fp32 sign tests: predicates must match numpy fp32
// rounding bit-exactly. contract(off) file-wide keeps exact paths exact
// (hipcc defaults to -ffp-contract=fast). Only the ellipse uses an approx
// screen (reciprocal-mul), with a rare bit-exact divide fallback.
#pragma clang fp contract(off)

#define NPTS 2097152
#define PPT  8                      // points per thread
#define NTHREADS (NPTS / PPT)       // 262144
#define STRIDE NTHREADS             // point k of thread t = t + k*STRIDE

// ws float layout:
//   TRI  [25][12]: ax,ay,d0y,d0x, bx,by,d1y,d1x, cx,cy,d2y,d2x  (numpy-rounded diffs)
//   CIRC [25][4] : ocx,ocy,r2,pad
//   ELL  [25][8] : ecx,ecy, 1/erx, 1/ery, erx, ery, pad,pad
//   COL  [75][4] : r,g,b,pad
#define TRI_OFF  0
#define CIRC_OFF 300
#define ELL_OFF  400
#define COL_OFF  600
// total 900 floats

// Ellipse screen band: recip-mul vs IEEE-div rel. error ~2.4e-7 at t~1;
// 1e-5 gives >40x margin (validated absmax 0.0 in rounds 1-2).
#define EPS_E 1e-5f

__global__ void vg_precompute(const float* __restrict__ p, float* __restrict__ ws) {
    int t = threadIdx.x;
    if (t < 25) {
        const float* cell = p + t * 28;
        float ax = cell[1], ay = cell[2], bx = cell[3], by = cell[4], cx = cell[5], cy = cell[6];
        float* o = ws + TRI_OFF + t * 12;
        o[0] = ax; o[1] = ay; o[2]  = by - ay; o[3]  = bx - ax;
        o[4] = bx; o[5] = by; o[6]  = cy - by; o[7]  = cx - bx;
        o[8] = cx; o[9] = cy; o[10] = ay - cy; o[11] = ax - cx;
        float* col = ws + COL_OFF + (3 * t + 0) * 4;
        col[0] = cell[8]; col[1] = cell[9]; col[2] = cell[10]; col[3] = 0.f;
    } else if (t < 50) {
        int c = t - 25;
        const float* cell = p + c * 28;
        float orr = cell[14];
        float* o = ws + CIRC_OFF + c * 4;
        o[0] = cell[12]; o[1] = cell[13]; o[2] = orr * orr; o[3] = 0.f;
        float* col = ws + COL_OFF + (3 * c + 1) * 4;
        col[0] = cell[16]; col[1] = cell[17]; col[2] = cell[18]; col[3] = 0.f;
    } else if (t < 75) {
        int c = t - 50;
        const float* cell = p + c * 28;
        float erx = cell[22], ery = cell[23];
        float* o = ws + ELL_OFF + c * 8;
        o[0] = cell[20]; o[1] = cell[21]; o[2] = 1.0f / erx; o[3] = 1.0f / ery;
        o[4] = erx; o[5] = ery; o[6] = 0.f; o[7] = 0.f;
        float* col = ws + COL_OFF + (3 * c + 2) * 4;
        col[0] = cell[25]; col[1] = cell[26]; col[2] = cell[27]; col[3] = 0.f;
    }
}

// Bit-exact numpy-order evaluation (real IEEE divides). Called only for points
// within the ellipse screen band (~1e-3 of points).
__device__ __noinline__ int exact_point(float px, float py, const float* __restrict__ ws) {
    int idx = -1;
#pragma clang loop unroll(disable)
    for (int c = 0; c < 25; ++c) {
        const float* tc = ws + TRI_OFF + c * 12;
        float e0 = (px - tc[0]) * tc[2]  - (py - tc[1]) * tc[3];
        float e1 = (px - tc[4]) * tc[6]  - (py - tc[5]) * tc[7];
        float e2 = (px - tc[8]) * tc[10] - (py - tc[9]) * tc[11];
        bool tin = (e0 >= 0.f && e1 >= 0.f && e2 >= 0.f) ||
                   (e0 <= 0.f && e1 <= 0.f && e2 <= 0.f);
        if (tin) idx = 3 * c;
        const float* cc = ws + CIRC_OFF + c * 4;
        float dx = px - cc[0], dy = py - cc[1];
        if (dx * dx + dy * dy <= cc[2]) idx = 3 * c + 1;
        const float* ec = ws + ELL_OFF + c * 8;
        float u = (px - ec[0]) / ec[4];   // IEEE division, numpy order
        float v = (py - ec[1]) / ec[5];
        if (u * u + v * v <= 1.0f) idx = 3 * c + 2;
    }
    return idx;
}

__global__ __launch_bounds__(256) void vg_main(const float* __restrict__ x,
                                               const float* __restrict__ ws,
                                               float* __restrict__ out) {
    int t = blockIdx.x * 256 + threadIdx.x;

    float px[PPT], py[PPT];
    int   idx[PPT];
    bool  unc[PPT];
    const float2* x2 = (const float2*)x;

#pragma unroll
    for (int k = 0; k < PPT; ++k) {
        float2 v = x2[t + k * STRIDE];   // coalesced: lanes contiguous at fixed k
        px[k] = v.x; py[k] = v.y;
        idx[k] = -1; unc[k] = false;
    }

    // Cells outer, points inner: 21 uniform scalar loads per cell amortized
    // over 8 points. unroll 2 (not 25): full unroll blows SGPR/SGPR-prefetch
    // budget — that was round 1-2's stall source.
#pragma unroll 2
    for (int c = 0; c < 25; ++c) {
        const float* tc = ws + TRI_OFF + c * 12;
        float ax = tc[0], ay = tc[1], d0y = tc[2],  d0x = tc[3];
        float bx = tc[4], by = tc[5], d1y = tc[6],  d1x = tc[7];
        float cx = tc[8], cy = tc[9], d2y = tc[10], d2x = tc[11];
        const float* cc = ws + CIRC_OFF + c * 4;
        float ocx = cc[0], ocy = cc[1], r2 = cc[2];
        const float* ec = ws + ELL_OFF + c * 8;
        float ecx = ec[0], ecy = ec[1], irx = ec[2], iry = ec[3];

#pragma unroll
        for (int k = 0; k < PPT; ++k) {
            float X = px[k], Y = py[k];

            // triangle (3c): bit-exact numpy order, contract(off)
            float e0 = (X - ax) * d0y - (Y - ay) * d0x;
            float e1 = (X - bx) * d1y - (Y - by) * d1x;
            float e2 = (X - cx) * d2y - (Y - cy) * d2x;
            float lo = __builtin_fminf(__builtin_fminf(e0, e1), e2);
            float hi = __builtin_fmaxf(__builtin_fmaxf(e0, e1), e2);
            bool tin = (lo >= 0.0f) || (hi <= 0.0f);   // == (all>=0)|(all<=0), exact
            idx[k] = tin ? 3 * c : idx[k];

            // circle (3c+1): bit-exact
            float dx = X - ocx, dy = Y - ocy;
            bool cin = (dx * dx + dy * dy) <= r2;
            idx[k] = cin ? 3 * c + 1 : idx[k];

            // ellipse (3c+2): reciprocal screen + band flag (fma ok here)
            float ex = X - ecx, ey = Y - ecy;
            float ua = ex * irx, va = ey * iry;
            float tt = __builtin_fmaf(ua, ua, va * va);
            bool ein = tt <= 1.0f;
            unc[k] = unc[k] || (__builtin_fabsf(tt - 1.0f) < EPS_E);
            idx[k] = ein ? 3 * c + 2 : idx[k];
        }
    }

    // Rare bit-exact fallback (ellipse band only), then color gather + store.
    const float4* coltab = (const float4*)(ws + COL_OFF);
#pragma unroll
    for (int k = 0; k < PPT; ++k) {
        if (__builtin_expect(unc[k], 0)) idx[k] = exact_point(px[k], py[k], ws);
        int ci = idx[k] < 0 ? 0 : idx[k];
        float4 col = coltab[ci];
        if (idx[k] < 0) { col.x = 0.f; col.y = 0.f; col.z = 0.f; }
        int p = t + k * STRIDE;
        out[3 * p + 0] = col.x;   // lanes contiguous at fixed k: coalesced
        out[3 * p + 1] = col.y;
        out[3 * p + 2] = col.z;
    }
}

extern "C" void kernel_launch(void* const* d_in, const int* in_sizes, int n_in,
                              void* d_out, int out_size, void* d_ws, size_t ws_size,
                              hipStream_t stream) {
    const float* x = (const float*)d_in[0];   // (NPTS, 2) fp32
    const float* p = (const float*)d_in[1];   // (700,)   fp32
    float* out = (float*)d_out;               // (NPTS, 3) fp32
    float* ws  = (float*)d_ws;                // >= 3.6 KB scratch

    vg_precompute<<<1, 128, 0, stream>>>(p, ws);
    vg_main<<<NTHREADS / 256, 256, 0, stream>>>(x, ws, out);
}

// Round 4
// 86.172 us; speedup vs baseline: 1.8694x; 1.3272x over previous
//
#include <hip/hip_runtime.h>

// Discrete color pick via fp32 sign tests: predicates must match numpy fp32
// rounding bit-exactly. contract(off) keeps the exact fallback exact; screens
// use explicit __builtin_fmaf with 2-sided bands + bit-exact 4-cell fallback.
#pragma clang fp contract(off)

#define NPTS 2097152
#define PPT  4
#define NTHREADS (NPTS / PPT)   // 524288

// Global ws float layout (written by vg_precompute every launch):
//   P_PACK [49][20]: padded 7x7 cell grid, 16 payload floats + 4 pad
//     [0..8]  tri affine: d0y,-d0x,k0, d1y,-d1x,k1, d2y,-d2x,k2  (k in fp64->fp32)
//     [9..11] circle: ocx,ocy,r2(=fl(orr*orr), numpy-identical)
//     [12..15] ellipse: ecx,ecy,1/erx,1/ery
//   P_COL  [76][4]: shape colors, entry 75 = black (no-hit)
//   P_ETRI [25][12], P_ECIR [25][4], P_EELL [25][8]: bit-exact numpy tables
#define P_PACK 0
#define P_COL  980
#define P_ETRI 1284
#define P_ECIR 1584
#define P_EELL 1684
// total 1884 floats (7.4 KB)

#define LDS_FLOATS 1284   // packed cells + colors staged to LDS

// Screen bands (2-sided; mismatch => bit-exact fallback):
//   tri affine vs numpy |delta| <= ~1.1e-7  -> 1e-6 (9x margin)
//   circ fma   vs numpy |delta| <= ~7e-9    -> 1e-7 (14x margin)
//   ell recip  vs numpy |delta| <= ~6e-7    -> 1e-5 (validated r1-r3, absmax 0)
#define EPS_T 1e-6f
#define EPS_C 1e-7f
#define EPS_E 1e-5f

__global__ void vg_precompute(const float* __restrict__ p, float* __restrict__ ws) {
    int t = threadIdx.x;
    if (t < 49) {
        int gi = t / 7, gj = t % 7;
        float* o = ws + P_PACK + t * 20;
        if (gi >= 1 && gi <= 5 && gj >= 1 && gj <= 5) {
            int c = (gi - 1) * 5 + (gj - 1);
            const float* cell = p + c * 28;
            float ax = cell[1], ay = cell[2], bx = cell[3], by = cell[4], cx = cell[5], cy = cell[6];
            float d0y = by - ay, d0x = bx - ax;   // numpy-rounded diffs
            float d1y = cy - by, d1x = cx - bx;
            float d2y = ay - cy, d2x = ax - cx;
            o[0] = d0y; o[1] = -d0x; o[2] = (float)((double)ay * (double)d0x - (double)ax * (double)d0y);
            o[3] = d1y; o[4] = -d1x; o[5] = (float)((double)by * (double)d1x - (double)bx * (double)d1y);
            o[6] = d2y; o[7] = -d2x; o[8] = (float)((double)cy * (double)d2x - (double)cx * (double)d2y);
            o[9]  = cell[12]; o[10] = cell[13]; o[11] = cell[14] * cell[14];
            o[12] = cell[20]; o[13] = cell[21]; o[14] = 1.0f / cell[22]; o[15] = 1.0f / cell[23];
        } else {
            // dummy border cell: all three tests false, never within any band
            o[0] = 0.f; o[1] = 0.f; o[2] = 10.f;    // e0 = +10
            o[3] = 0.f; o[4] = 0.f; o[5] = -10.f;   // e1 = -10 -> mixed signs, outside band
            o[6] = 0.f; o[7] = 0.f; o[8] = 0.f;     // e2 = 0
            o[9] = 0.f; o[10] = 0.f; o[11] = -10.f; // r2 = -10: d2 >= 0 > r2, |d2-r2| >= 10
            o[12] = 1000.f; o[13] = 1000.f; o[14] = 1.f; o[15] = 1.f;  // te ~ 1e6
        }
        o[16] = 0.f; o[17] = 0.f; o[18] = 0.f; o[19] = 0.f;
    } else if (t < 74) {
        int c = t - 49;
        const float* cell = p + c * 28;
        float ax = cell[1], ay = cell[2], bx = cell[3], by = cell[4], cx = cell[5], cy = cell[6];
        float* o = ws + P_ETRI + c * 12;
        o[0] = ax; o[1] = ay; o[2]  = by - ay; o[3]  = bx - ax;
        o[4] = bx; o[5] = by; o[6]  = cy - by; o[7]  = cx - bx;
        o[8] = cx; o[9] = cy; o[10] = ay - cy; o[11] = ax - cx;
        float* col = ws + P_COL + (3 * c + 0) * 4;
        col[0] = cell[8]; col[1] = cell[9]; col[2] = cell[10]; col[3] = 0.f;
    } else if (t < 99) {
        int c = t - 74;
        const float* cell = p + c * 28;
        float orr = cell[14];
        float* o = ws + P_ECIR + c * 4;
        o[0] = cell[12]; o[1] = cell[13]; o[2] = orr * orr; o[3] = 0.f;
        float* col = ws + P_COL + (3 * c + 1) * 4;
        col[0] = cell[16]; col[1] = cell[17]; col[2] = cell[18]; col[3] = 0.f;
    } else if (t < 124) {
        int c = t - 99;
        const float* cell = p + c * 28;
        float* o = ws + P_EELL + c * 8;
        o[0] = cell[20]; o[1] = cell[21]; o[2] = 0.f; o[3] = 0.f;
        o[4] = cell[22]; o[5] = cell[23]; o[6] = 0.f; o[7] = 0.f;
        float* col = ws + P_COL + (3 * c + 2) * 4;
        col[0] = cell[25]; col[1] = cell[26]; col[2] = cell[27]; col[3] = 0.f;
    } else if (t == 124) {
        float* col = ws + P_COL + 75 * 4;   // no-hit -> black
        col[0] = 0.f; col[1] = 0.f; col[2] = 0.f; col[3] = 0.f;
    }
}

// Bit-exact numpy-order evaluation over the 4 candidate cells only (exact for
// numpy too: non-candidate shapes are >= 5e-4 away geometrically, while numpy's
// fp32 sign-test reach is ~3e-7). Rare: only band-flagged points get here.
__device__ __noinline__ int exact_point(float px, float py, int ihi, int jhi,
                                        const float* __restrict__ ws) {
    int idx = -1;
#pragma clang loop unroll(disable)
    for (int s = 0; s < 4; ++s) {
        int gi = ihi + (s >> 1), gj = jhi + (s & 1);   // increasing cell order
        if (gi < 1 || gi > 5 || gj < 1 || gj > 5) continue;
        int c = 5 * (gi - 1) + (gj - 1);
        const float* tc = ws + P_ETRI + c * 12;
        float e0 = (px - tc[0]) * tc[2]  - (py - tc[1]) * tc[3];
        float e1 = (px - tc[4]) * tc[6]  - (py - tc[5]) * tc[7];
        float e2 = (px - tc[8]) * tc[10] - (py - tc[9]) * tc[11];
        bool tin = (e0 >= 0.f && e1 >= 0.f && e2 >= 0.f) ||
                   (e0 <= 0.f && e1 <= 0.f && e2 <= 0.f);
        if (tin) idx = 3 * c;
        const float* cc = ws + P_ECIR + c * 4;
        float dx = px - cc[0], dy = py - cc[1];
        if (dx * dx + dy * dy <= cc[2]) idx = 3 * c + 1;
        const float* ec = ws + P_EELL + c * 8;
        float u = (px - ec[0]) / ec[4];   // IEEE division, numpy order
        float v = (py - ec[1]) / ec[5];
        if (u * u + v * v <= 1.0f) idx = 3 * c + 2;
    }
    return idx;
}

__global__ __launch_bounds__(256) void vg_main(const float* __restrict__ x,
                                               const float* __restrict__ ws,
                                               float* __restrict__ out) {
    __shared__ float lds[LDS_FLOATS];
    int tl = threadIdx.x;
    int t  = blockIdx.x * 256 + tl;

    // Stage packed cells + colors (1284 floats = 321 float4) into LDS.
    {
        float4* l4 = (float4*)lds;
        const float4* g4 = (const float4*)ws;
        l4[tl] = g4[tl];
        if (tl < LDS_FLOATS / 4 - 256) l4[256 + tl] = g4[256 + tl];
    }
    __syncthreads();

    const float4* x4 = (const float4*)x;
    float4 xa = x4[2 * t], xb = x4[2 * t + 1];   // points 4t..4t+3, contiguous
    float PX[PPT] = {xa.x, xa.z, xb.x, xb.z};
    float PY[PPT] = {xa.y, xa.w, xb.y, xb.w};
    int idx[PPT], ihi[PPT], jhi[PPT];
    bool unc[PPT];

#pragma unroll
    for (int k = 0; k < PPT; ++k) {
        idx[k] = -1; unc[k] = false;
        // candidate columns {i_hi-1, i_hi}: i_hi = floor((X+0.0805)*5); padded gi = i+1
        ihi[k] = (int)floorf(__builtin_fmaf(PX[k], 5.0f, 0.4025f));
        jhi[k] = (int)floorf(__builtin_fmaf(PY[k], 5.0f, 0.4025f));
    }

#pragma unroll
    for (int a = 0; a < 2; ++a) {
#pragma unroll
        for (int b = 0; b < 2; ++b) {
#pragma unroll
            for (int k = 0; k < PPT; ++k) {
                int gi = ihi[k] + a, gj = jhi[k] + b;           // in [0,6]
                const float4* c4 = (const float4*)(lds + (gi * 7 + gj) * 20);
                float4 q0 = c4[0], q1 = c4[1], q2 = c4[2], q3 = c4[3];
                float X = PX[k], Y = PY[k];

                // triangle: affine screen, 2-sided band
                float e0 = __builtin_fmaf(X, q0.x, __builtin_fmaf(Y, q0.y, q0.z));
                float e1 = __builtin_fmaf(X, q0.w, __builtin_fmaf(Y, q1.x, q1.y));
                float e2 = __builtin_fmaf(X, q1.z, __builtin_fmaf(Y, q1.w, q2.x));
                float lo = __builtin_fminf(__builtin_fminf(e0, e1), e2);
                float hi = __builtin_fmaxf(__builtin_fmaxf(e0, e1), e2);
                bool ts = (lo >= EPS_T) || (hi <= -EPS_T);
                bool tr = (lo >= -EPS_T) || (hi <= EPS_T);
                unc[k] = unc[k] || (ts != tr);
                int sid = 15 * gi + 3 * gj - 18;                 // 3*(5i+j)
                idx[k] = ts ? sid : idx[k];

                // circle: centered fma screen
                float dx = X - q2.y, dy = Y - q2.z;
                float tcirc = __builtin_fmaf(dx, dx, dy * dy);
                unc[k] = unc[k] || (__builtin_fabsf(tcirc - q2.w) < EPS_C);
                idx[k] = (tcirc <= q2.w) ? sid + 1 : idx[k];

                // ellipse: reciprocal screen
                float ex = X - q3.x, ey = Y - q3.y;
                float u = ex * q3.z, v = ey * q3.w;
                float te = __builtin_fmaf(u, u, v * v);
                unc[k] = unc[k] || (__builtin_fabsf(te - 1.0f) < EPS_E);
                idx[k] = (te <= 1.0f) ? sid + 2 : idx[k];
            }
        }
    }

    // Rare bit-exact fallback for band-flagged points.
#pragma unroll
    for (int k = 0; k < PPT; ++k)
        if (__builtin_expect(unc[k], 0))
            idx[k] = exact_point(PX[k], PY[k], ihi[k], jhi[k], ws);

    // Color gather from LDS (entry 75 = black for no-hit) + packed store.
    const float4* col4 = (const float4*)(lds + P_COL);
    float4 c0 = col4[idx[0] < 0 ? 75 : idx[0]];
    float4 c1 = col4[idx[1] < 0 ? 75 : idx[1]];
    float4 c2 = col4[idx[2] < 0 ? 75 : idx[2]];
    float4 c3 = col4[idx[3] < 0 ? 75 : idx[3]];

    float4* out4 = (float4*)out;
    out4[3 * t + 0] = make_float4(c0.x, c0.y, c0.z, c1.x);
    out4[3 * t + 1] = make_float4(c1.y, c1.z, c2.x, c2.y);
    out4[3 * t + 2] = make_float4(c2.z, c3.x, c3.y, c3.z);
}

extern "C" void kernel_launch(void* const* d_in, const int* in_sizes, int n_in,
                              void* d_out, int out_size, void* d_ws, size_t ws_size,
                              hipStream_t stream) {
    const float* x = (const float*)d_in[0];   // (NPTS, 2) fp32
    const float* p = (const float*)d_in[1];   // (700,)   fp32
    float* out = (float*)d_out;               // (NPTS, 3) fp32
    float* ws  = (float*)d_ws;                // >= 7.6 KB scratch

    vg_precompute<<<1, 128, 0, stream>>>(p, ws);
    vg_main<<<NTHREADS / 256, 256, 0, stream>>>(x, ws, out);
}